// Round 3
// baseline (252.869 us; speedup 1.0000x reference)
//
#include <hip/hip_runtime.h>
#include <math.h>

#define N_NODES 50000
#define N_EDGES 800000
#define HID 128
#define CAP 64                              // max in-degree; Poisson(16) -> P(>64) ~ 1e-18

// fused1 grid partition: [scatter | Wo-cvt | qkv-GEMM]
#define SCAT_TH   (N_EDGES / 8)             // 100000 threads, 8 edges each
#define SCAT_BLK  ((SCAT_TH + 255) / 256)   // 391
#define WOCVT_BLK 16                        // 4096 float4 / 256
#define QKV_BX    ((N_NODES + 31) / 32)     // 1563
#define QKV_BLKS  (QKV_BX * 2)              // 3126 (y-half folded into x)
#define FUSED1_BLK (SCAT_BLK + WOCVT_BLK + QKV_BLKS)

#define ATTN_BLK  ((N_NODES + 3) / 4)       // 12500
#define OUT_BLK   ((N_NODES + 63) / 64)     // 782

typedef _Float16 f16_t;
typedef f16_t f16x8 __attribute__((ext_vector_type(8)));
typedef f16_t f16x2 __attribute__((ext_vector_type(2)));
typedef float f32x4 __attribute__((ext_vector_type(4)));

__device__ __forceinline__ ushort f2h_bits(float x) {
    union { f16_t h; ushort u; } c; c.h = (f16_t)x; return c.u;
}
__device__ __forceinline__ f16x2 as_h2(uint u) {
    union { uint u_; f16x2 h; } c; c.u_ = u; return c.h;
}
// load 8 consecutive f32 and convert to f16x8 (2x dwordx4 + pk-cvts)
__device__ __forceinline__ f16x8 ldcvt8(const float* __restrict__ p) {
    float4 f0 = *(const float4*)p;
    float4 f1 = *(const float4*)(p + 4);
    f16x8 r;
    r[0] = (f16_t)f0.x; r[1] = (f16_t)f0.y; r[2] = (f16_t)f0.z; r[3] = (f16_t)f0.w;
    r[4] = (f16_t)f1.x; r[5] = (f16_t)f1.y; r[6] = (f16_t)f1.z; r[7] = (f16_t)f1.w;
    return r;
}

// ---------------------------------------------------------------------------
// fused1: one grid, three independent jobs co-scheduled (round-2 post-mortem:
// attn is memory-pattern-bound at ~56 us; the remaining 182 us is the serial
// prep->qkv chain. hf intermediate eliminated — qkv converts f32 in-register;
// scatter hides under the GEMM instead of a serial dispatch).
//   blocks [0, SCAT_BLK)      : edge scatter — 8 edges/thread, int4 loads,
//                               8 returning atomics in flight, 64B-padded cnt
//   next WOCVT_BLK            : Wo f32 -> f16 with k-axis PERMUTED head-major
//                               p = (k&7)*16 + (k>>3)  (matches attn ao layout)
//   next QKV_BLKS             : QKV projection, MFMA 16x16x32 f16, flat
//                               pipeline; A (h) and B (Wq/Wk/Wv) loaded f32 +
//                               converted in-register (W fully L2-resident).
// qkv layout (unchanged from round 1/2, verified): wave T = head, cols
// c = 16*(mrow&7) + (mrow>=8)*8 + T; pack p = 8T + (mrow&7):
//   qp[row*64 + 8h + t]  = [q_{2t} | q_{2t+1}] of head h (*0.25)
//   kv[row*64 + 8h + t]  = { [k_2t|k_2t+1], [v_2t|v_2t+1] } of head h
__global__ __launch_bounds__(256) void fused1(
    const float* __restrict__ h,
    const float* __restrict__ Wq, const float* __restrict__ Wk,
    const float* __restrict__ Wv, const float* __restrict__ Wo,
    const float* __restrict__ bq, const float* __restrict__ bk,
    const float* __restrict__ bv,
    const int* __restrict__ rows, const int* __restrict__ cols,
    int* __restrict__ cnt, ushort* __restrict__ slots,
    ushort* __restrict__ wfo,
    uint* __restrict__ qp, uint2* __restrict__ kv)
{
    const int b = blockIdx.x;
    const int tid = threadIdx.x;

    if (b < SCAT_BLK) {
        // ---------------- edge scatter ----------------
        const int t = b * 256 + tid;
        if (t < SCAT_TH) {
            const int4* r4 = (const int4*)rows + (size_t)t * 2;
            const int4* c4 = (const int4*)cols + (size_t)t * 2;
            int4 ra = r4[0], rb2 = r4[1];
            int4 ca = c4[0], cb = c4[1];
            const int r[8] = {ra.x, ra.y, ra.z, ra.w, rb2.x, rb2.y, rb2.z, rb2.w};
            const int c[8] = {ca.x, ca.y, ca.z, ca.w, cb.x, cb.y, cb.z, cb.w};
            int p[8];
#pragma unroll
            for (int u = 0; u < 8; ++u)
                p[u] = atomicAdd(&cnt[r[u] << 4], 1);     // 64B-padded counter
#pragma unroll
            for (int u = 0; u < 8; ++u)
                if (p[u] < CAP) slots[(size_t)r[u] * CAP + p[u]] = (ushort)c[u];
        }
        return;
    }
    if (b < SCAT_BLK + WOCVT_BLK) {
        // ---------------- Wo cvt + head-major k-permute ----------------
        const int i = (b - SCAT_BLK) * 256 + tid;         // [0, 4096) float4s
        float4 f = ((const float4*)Wo)[i];
        const int c  = i >> 5;            // output col (Wo row)
        const int k0 = (i & 31) * 4;      // hidden k of f.x
        const int d  = k0 >> 3;           // dim group (k0 % 8 in {0,4})
        ushort* wo = wfo + c * HID + d;
        wo[((k0 + 0) & 7) << 4] = f2h_bits(f.x);
        wo[((k0 + 1) & 7) << 4] = f2h_bits(f.y);
        wo[((k0 + 2) & 7) << 4] = f2h_bits(f.z);
        wo[((k0 + 3) & 7) << 4] = f2h_bits(f.w);
        return;
    }

    // ---------------- QKV projection ----------------
    const int qb   = b - (SCAT_BLK + WOCVT_BLK);          // [0, 3126)
    const int by   = (qb >= QKV_BX) ? 1 : 0;
    const int bx   = qb - by * QKV_BX;
    const int lane = tid & 63;
    const int wid  = tid >> 6;
    const int mrow = lane & 15;
    const int quad = lane >> 4;
    const int rb   = bx * 32;
    const int T    = by * 4 + wid;                        // head 0..7
    const int c    = ((mrow & 7) << 4) + ((mrow >> 3) << 3) + T;  // hidden col

    // A fragments (2 strips x 4 k-chunks), f32 -> f16 in-register
    f16x8 a[2][4];
#pragma unroll
    for (int s = 0; s < 2; ++s) {
        int ar = rb + s * 16 + mrow;
        if (ar >= N_NODES) ar = N_NODES - 1;
        const float* ap = h + (size_t)ar * HID + quad * 8;
#pragma unroll
        for (int kc = 0; kc < 4; ++kc) a[s][kc] = ldcvt8(ap + kc * 32);
    }
    // W fragments: all three mats, f32 -> f16 in-register (L2-resident)
    f16x8 bQ[4], bK[4], bV[4];
#pragma unroll
    for (int kc = 0; kc < 4; ++kc) {
        const int off = c * HID + kc * 32 + quad * 8;
        bQ[kc] = ldcvt8(Wq + off);
        bK[kc] = ldcvt8(Wk + off);
        bV[kc] = ldcvt8(Wv + off);
    }

    f32x4 aq[2], ak[2], av[2];
#pragma unroll
    for (int s = 0; s < 2; ++s) {
        aq[s] = (f32x4){0.f, 0.f, 0.f, 0.f};
        ak[s] = (f32x4){0.f, 0.f, 0.f, 0.f};
        av[s] = (f32x4){0.f, 0.f, 0.f, 0.f};
    }
#pragma unroll
    for (int s = 0; s < 2; ++s)
#pragma unroll
        for (int kc = 0; kc < 4; ++kc) {
            aq[s] = __builtin_amdgcn_mfma_f32_16x16x32_f16(a[s][kc], bQ[kc], aq[s], 0, 0, 0);
            ak[s] = __builtin_amdgcn_mfma_f32_16x16x32_f16(a[s][kc], bK[kc], ak[s], 0, 0, 0);
            av[s] = __builtin_amdgcn_mfma_f32_16x16x32_f16(a[s][kc], bV[kc], av[s], 0, 0, 0);
        }

    const float bqc = bq[c], bkc = bk[c], bvc = bv[c];
    const bool  lo  = (mrow & 8) == 0;
    const int   i   = mrow & 7;                          // = dim-pair t
#pragma unroll
    for (int s = 0; s < 2; ++s)
#pragma unroll
        for (int r = 0; r < 4; ++r) {
            const int orow = rb + s * 16 + quad * 4 + r;
            uint qv = f2h_bits((aq[s][r] + bqc) * 0.25f);  // q pre-scaled 1/sqrt(d)
            uint kb = f2h_bits(ak[s][r] + bkc);
            uint vb = f2h_bits(av[s][r] + bvc);
            uint qh = __shfl_xor((int)qv, 8);
            uint kh = __shfl_xor((int)kb, 8);
            uint vh = __shfl_xor((int)vb, 8);
            if (lo && orow < N_NODES) {
                const size_t base = (size_t)orow * 64 + 8 * T + i;
                qp[base] = qv | (qh << 16);
                kv[base] = make_uint2(kb | (kh << 16), vb | (vh << 16));
            }
        }
}

// ---------------------------------------------------------------------------
// attn, hybrid structure (unchanged — pinned at the random-512B-gather memory
// ceiling: two different structures both measured 56 us / 182 MB / 3.55 TB/s).
// Lane = (half, t): half = lane>>5 picks which edge of a pair, t = lane&31
// owns the row's uint4 slot t. 32 lanes read one FULL 512 B kv row
// contiguously; wave covers 2 edges per load. Head = 4-lane quad -> butterfly
// is 2 shfls (xor 1,2). 8-edge unroll, 4 independent register banks.
__device__ __forceinline__ void pair_acc(uint4 rr, uint2 qu,
                                         float& l, float* O)
{
    float p = __builtin_amdgcn_fdot2(as_h2(rr.x), as_h2(qu.x), 0.f, false);
    p = __builtin_amdgcn_fdot2(as_h2(rr.z), as_h2(qu.y), p, false);
    p += __shfl_xor(p, 1);
    p += __shfl_xor(p, 2);
    const float ex = __expf(p);
    l += ex;
    const f16x2 va = as_h2(rr.y), vb = as_h2(rr.w);
    O[0] += ex * (float)va[0];
    O[1] += ex * (float)va[1];
    O[2] += ex * (float)vb[0];
    O[3] += ex * (float)vb[1];
}

__device__ __forceinline__ void pair_acc_m(uint4 rr, uint2 qu, bool ok,
                                           float& l, float* O)
{
    float p = __builtin_amdgcn_fdot2(as_h2(rr.x), as_h2(qu.x), 0.f, false);
    p = __builtin_amdgcn_fdot2(as_h2(rr.z), as_h2(qu.y), p, false);
    p += __shfl_xor(p, 1);
    p += __shfl_xor(p, 2);
    const float ex = ok ? __expf(p) : 0.f;
    l += ex;
    const f16x2 va = as_h2(rr.y), vb = as_h2(rr.w);
    O[0] += ex * (float)va[0];
    O[1] += ex * (float)va[1];
    O[2] += ex * (float)vb[0];
    O[3] += ex * (float)vb[1];
}

__global__ __launch_bounds__(256) void attn(
    const uint* __restrict__ qp, const uint2* __restrict__ kv,
    const int* __restrict__ cnt, const ushort* __restrict__ slots,
    ushort* __restrict__ ao)
{
    const int lane = threadIdx.x & 63;
    const int node = blockIdx.x * 4 + (threadIdx.x >> 6);
    if (node >= N_NODES) return;
    const int half = lane >> 5;              // edge-of-pair selector
    const int t    = lane & 31;              // uint4 slot in row

    // q dim-pairs (2t, 2t+1): head t>>2, dims 4(t&3)..+3 (pre-scaled)
    const uint2 qu = *(const uint2*)(qp + (size_t)node * 64 + 2 * t);

    int deg = cnt[node << 4];                // padded counter
    if (deg > CAP) deg = CAP;
    const int myslot = (lane < deg) ? (int)slots[(size_t)node * CAP + lane] : 0;

    float l0 = 0.f, l1 = 0.f, l2 = 0.f, l3 = 0.f;
    float O0[4] = {0,0,0,0}, O1[4] = {0,0,0,0};
    float O2[4] = {0,0,0,0}, O3[4] = {0,0,0,0};

    const uint4* base = (const uint4*)kv;    // row = 32 uint4

    int j = 0;
    for (; j + 8 <= deg; j += 8) {
        const int s0 = __shfl(myslot, j + half);
        const int s1 = __shfl(myslot, j + 2 + half);
        const int s2 = __shfl(myslot, j + 4 + half);
        const int s3 = __shfl(myslot, j + 6 + half);
        const uint4 r0 = base[(size_t)s0 * 32 + t];
        const uint4 r1 = base[(size_t)s1 * 32 + t];
        const uint4 r2 = base[(size_t)s2 * 32 + t];
        const uint4 r3 = base[(size_t)s3 * 32 + t];
        pair_acc(r0, qu, l0, O0);
        pair_acc(r1, qu, l1, O1);
        pair_acc(r2, qu, l2, O2);
        pair_acc(r3, qu, l3, O3);
    }
    for (; j < deg; j += 2) {
        const int e = j + half;
        const int s = __shfl(myslot, e);     // lanes >= deg hold myslot=0: safe
        const uint4 rr = base[(size_t)s * 32 + t];
        pair_acc_m(rr, qu, e < deg, l0, O0);
    }

    float l = (l0 + l1) + (l2 + l3);
    float Of[4];
    Of[0] = (O0[0] + O1[0]) + (O2[0] + O3[0]);
    Of[1] = (O0[1] + O1[1]) + (O2[1] + O3[1]);
    Of[2] = (O0[2] + O1[2]) + (O2[2] + O3[2]);
    Of[3] = (O0[3] + O1[3]) + (O2[3] + O3[3]);

    // merge the two halves (each processed its own edge subset)
    l += __shfl_xor(l, 32);
    Of[0] += __shfl_xor(Of[0], 32);
    Of[1] += __shfl_xor(Of[1], 32);
    Of[2] += __shfl_xor(Of[2], 32);
    Of[3] += __shfl_xor(Of[3], 32);

    const float inv = (l > 0.f) ? 1.f / l : 0.f;   // deg-0 -> 0 (bo added later)

    if (half == 0) {                        // lanes 0..31 store 8 B each, contiguous
        ushort4 st;
        st.x = f2h_bits(Of[0] * inv);
        st.y = f2h_bits(Of[1] * inv);
        st.z = f2h_bits(Of[2] * inv);
        st.w = f2h_bits(Of[3] * inv);
        *(ushort4*)(ao + (size_t)node * HID + 4 * t) = st;
    }
}

// ---------------------------------------------------------------------------
// Output projection, flat pipeline: all 24 loads (16 A + 8 W f16) up front,
// then 32 MFMAs. 64-row blocks, wave owns 2 n-tiles (32 cols).
// A (ao) is head-major in k; wfo is the k-permuted Wo — the MFMA contraction
// index just runs over the permuted order on both sides.
__global__ __launch_bounds__(256) void gemm_out(
    const ushort* __restrict__ A, const ushort* __restrict__ wfo,
    const float* __restrict__ bias, float* __restrict__ out)
{
    const int lane = threadIdx.x & 63;
    const int wid  = threadIdx.x >> 6;
    const int mrow = lane & 15;
    const int quad = lane >> 4;
    const int rb   = blockIdx.x * 64;

    const int c0 = wid * 32 + mrow;
    const int c1 = c0 + 16;

    f16x8 a[4][4];
#pragma unroll
    for (int s = 0; s < 4; ++s) {
        int ar = rb + s * 16 + mrow;
        if (ar >= N_NODES) ar = N_NODES - 1;
        const ushort* ap = A + (size_t)ar * HID + quad * 8;
#pragma unroll
        for (int kc = 0; kc < 4; ++kc) a[s][kc] = *(const f16x8*)(ap + kc * 32);
    }
    f16x8 b0[4], b1[4];
#pragma unroll
    for (int kc = 0; kc < 4; ++kc) {
        b0[kc] = *(const f16x8*)(wfo + c0 * HID + kc * 32 + quad * 8);
        b1[kc] = *(const f16x8*)(wfo + c1 * HID + kc * 32 + quad * 8);
    }

    f32x4 acc[4][2];
#pragma unroll
    for (int s = 0; s < 4; ++s) {
        acc[s][0] = (f32x4){0.f, 0.f, 0.f, 0.f};
        acc[s][1] = (f32x4){0.f, 0.f, 0.f, 0.f};
    }
#pragma unroll
    for (int s = 0; s < 4; ++s)
#pragma unroll
        for (int kc = 0; kc < 4; ++kc) {
            acc[s][0] = __builtin_amdgcn_mfma_f32_16x16x32_f16(a[s][kc], b0[kc], acc[s][0], 0, 0, 0);
            acc[s][1] = __builtin_amdgcn_mfma_f32_16x16x32_f16(a[s][kc], b1[kc], acc[s][1], 0, 0, 0);
        }

    const float bc0 = bias[c0], bc1 = bias[c1];
#pragma unroll
    for (int s = 0; s < 4; ++s)
#pragma unroll
        for (int r = 0; r < 4; ++r) {
            const int orow = rb + s * 16 + quad * 4 + r;
            if (orow < N_NODES) {
                out[(size_t)orow * HID + c0] = acc[s][0][r] + bc0;
                out[(size_t)orow * HID + c1] = acc[s][1][r] + bc1;
            }
        }
}

// ---------------------------------------------------------------------------
extern "C" void kernel_launch(void* const* d_in, const int* in_sizes, int n_in,
                              void* d_out, int out_size, void* d_ws, size_t ws_size,
                              hipStream_t stream)
{
    const float* h    = (const float*)d_in[0];
    const int*   rows = (const int*)  d_in[1];
    const int*   cols = (const int*)  d_in[2];
    const float* Wq   = (const float*)d_in[3];
    const float* bq   = (const float*)d_in[4];
    const float* Wk   = (const float*)d_in[5];
    const float* bk   = (const float*)d_in[6];
    const float* Wv   = (const float*)d_in[7];
    const float* bv   = (const float*)d_in[8];
    const float* Wo   = (const float*)d_in[9];
    const float* bo   = (const float*)d_in[10];
    float* out = (float*)d_out;

    char* ws = (char*)d_ws;
    uint*   qp    = (uint*)ws;    ws += (size_t)N_NODES * 64 * 4;   // 12.8 MB
    uint2*  kv    = (uint2*)ws;   ws += (size_t)N_NODES * 64 * 8;   // 25.6 MB
    ushort* ao    = (ushort*)ws;  ws += (size_t)N_NODES * HID * 2;  // 12.8 MB
    ushort* wfo   = (ushort*)ws;  ws += 16384 * 2;                  // 32 KB
    int*    cnt   = (int*)ws;     ws += (size_t)N_NODES * 64;       // 3.2 MB padded
    ushort* slots = (ushort*)ws;  // N*CAP ushorts, 6.4 MB

    hipMemsetAsync(cnt, 0, (size_t)N_NODES * 64, stream);

    dim3 blk(256);
    fused1<<<FUSED1_BLK, blk, 0, stream>>>(h, Wq, Wk, Wv, Wo, bq, bk, bv,
                                           rows, cols, cnt, slots, wfo, qp, kv);
    attn<<<ATTN_BLK, blk, 0, stream>>>(qp, kv, cnt, slots, ao);
    gemm_out<<<OUT_BLK, blk, 0, stream>>>(ao, wfo, bo, out);
}

// Round 4
// 251.054 us; speedup vs baseline: 1.0072x; 1.0072x over previous
//
#include <hip/hip_runtime.h>
#include <math.h>

#define N_NODES 50000
#define N_EDGES 800000
#define HID 128
#define CAP 64                              // max in-degree; Poisson(16) -> P(>64) ~ 1e-18

// prep grid partition: [scatter | weight-cvt | h-cvt]  (R2-verified structure:
// scatter latency hides under streaming cvt; NEVER co-schedule scatter w/ MFMA)
#define SCAT_TH   (N_EDGES / 8)             // 100000 threads, 8 edges each
#define SCAT_BLK  ((SCAT_TH + 255) / 256)   // 391
#define WCVT_BLK  64                        // 4 mats x 4096 float4 / 256
#define HCVT_BLK  (N_NODES * HID / 4 / 256) // 6250
#define PREP_BLK  (SCAT_BLK + WCVT_BLK + HCVT_BLK)

#define QKV_BX    ((N_NODES + 31) / 32)     // 1563 blocks, 512 threads (8 head-waves)
#define AO_BLK    ((N_NODES + 63) / 64)     // 782 blocks, 512 threads (attn+out fused)

typedef _Float16 f16_t;
typedef f16_t f16x8 __attribute__((ext_vector_type(8)));
typedef f16_t f16x2 __attribute__((ext_vector_type(2)));
typedef float f32x4 __attribute__((ext_vector_type(4)));

__device__ __forceinline__ ushort f2h_bits(float x) {
    union { f16_t h; ushort u; } c; c.h = (f16_t)x; return c.u;
}
__device__ __forceinline__ f16x2 as_h2(uint u) {
    union { uint u_; f16x2 h; } c; c.u_ = u; return c.h;
}

// ---------------------------------------------------------------------------
// prep: one grid, three independent jobs co-scheduled (exact R2 structure).
//   blocks [0, SCAT_BLK)    : edge scatter — 8 edges/thread, int4 loads,
//                             8 returning atomics in flight, 64B-padded cnt
//   next WCVT_BLK           : Wq/Wk/Wv f32 -> f16 (hidden-k order);
//                             Wo f32 -> f16 with k-axis PERMUTED head-major
//                             p = (k&7)*16 + (k>>3)  (matches attn ao layout)
//   next HCVT_BLK           : h f32 -> f16 (BW-bound; hides scatter latency)
__global__ __launch_bounds__(256) void prep(
    const float* __restrict__ h,
    const float* __restrict__ Wq, const float* __restrict__ Wk,
    const float* __restrict__ Wv, const float* __restrict__ Wo,
    ushort* __restrict__ hf, ushort* __restrict__ wf,     // wf: 4 mats concat
    const int* __restrict__ rows, const int* __restrict__ cols,
    int* __restrict__ cnt, ushort* __restrict__ slots)
{
    const int b = blockIdx.x;
    const int tid = threadIdx.x;

    if (b < SCAT_BLK) {
        const int t = b * 256 + tid;
        if (t < SCAT_TH) {
            const int4* r4 = (const int4*)rows + (size_t)t * 2;
            const int4* c4 = (const int4*)cols + (size_t)t * 2;
            int4 ra = r4[0], rb2 = r4[1];
            int4 ca = c4[0], cb = c4[1];
            const int r[8] = {ra.x, ra.y, ra.z, ra.w, rb2.x, rb2.y, rb2.z, rb2.w};
            const int c[8] = {ca.x, ca.y, ca.z, ca.w, cb.x, cb.y, cb.z, cb.w};
            int p[8];
#pragma unroll
            for (int u = 0; u < 8; ++u)
                p[u] = atomicAdd(&cnt[r[u] << 4], 1);     // 64B-padded counter
#pragma unroll
            for (int u = 0; u < 8; ++u)
                if (p[u] < CAP) slots[(size_t)r[u] * CAP + p[u]] = (ushort)c[u];
        }
    } else if (b < SCAT_BLK + WCVT_BLK) {
        const int t = (b - SCAT_BLK) * 256 + tid;         // [0, 16384)
        const int m = t >> 12, i = t & 4095;
        const float* src = (m == 0) ? Wq : (m == 1) ? Wk : (m == 2) ? Wv : Wo;
        float4 f = ((const float4*)src)[i];
        if (m < 3) {
            ushort4 o;
            o.x = f2h_bits(f.x); o.y = f2h_bits(f.y);
            o.z = f2h_bits(f.z); o.w = f2h_bits(f.w);
            ((ushort4*)(wf + m * 16384))[i] = o;
        } else {
            // Wo: permute k-axis to head-major p = head*16 + dim
            const int c  = i >> 5;            // output col (Wo row)
            const int k0 = (i & 31) * 4;      // hidden k of f.x
            const int d  = k0 >> 3;           // dim group (k0 % 8 in {0,4})
            ushort* wo = wf + 3 * 16384 + c * HID + d;
            wo[((k0 + 0) & 7) << 4] = f2h_bits(f.x);
            wo[((k0 + 1) & 7) << 4] = f2h_bits(f.y);
            wo[((k0 + 2) & 7) << 4] = f2h_bits(f.z);
            wo[((k0 + 3) & 7) << 4] = f2h_bits(f.w);
        }
    } else {
        const int t = (b - SCAT_BLK - WCVT_BLK) * 256 + tid;  // [0, 1.6M)
        float4 f = ((const float4*)h)[t];
        ushort4 o;
        o.x = f2h_bits(f.x); o.y = f2h_bits(f.y);
        o.z = f2h_bits(f.z); o.w = f2h_bits(f.w);
        ((ushort4*)hf)[t] = o;
    }
}

// ---------------------------------------------------------------------------
// QKV projection, MFMA 16x16x32 f16, flat pipeline — now 512-thread blocks:
// all 8 head-waves of a 32-row strip share one CU, so A (hf) is fetched once
// (L1 reuse, was 2x across blockIdx.y) and the 8 per-head 32B qp / 64B kv
// chunks of each output row are written from the same CU at the same time ->
// full-line L2 write-combining (kills partial-line write amplification).
// Layout (verified rounds 1-3): wave T = head, cols c = 16*(mrow&7) +
// (mrow>=8)*8 + T; pack p = 8T + (mrow&7):
//   qp[row*64 + 8h + t]  = [q_{2t} | q_{2t+1}] of head h (*0.25)
//   kv[row*64 + 8h + t]  = { [k_2t|k_2t+1], [v_2t|v_2t+1] } of head h
__global__ __launch_bounds__(512) void gemm_qkv(
    const ushort* __restrict__ hf, const ushort* __restrict__ wf,
    const float* __restrict__ bq, const float* __restrict__ bk,
    const float* __restrict__ bv,
    uint* __restrict__ qp, uint2* __restrict__ kv)
{
    const int tid  = threadIdx.x;
    const int lane = tid & 63;
    const int T    = tid >> 6;                           // head 0..7
    const int mrow = lane & 15;
    const int quad = lane >> 4;
    const int rb   = blockIdx.x * 32;
    const int c    = ((mrow & 7) << 4) + ((mrow >> 3) << 3) + T;  // hidden col

    // A fragments (2 strips x 4 k-chunks), row-clamped at N
    f16x8 a[2][4];
#pragma unroll
    for (int s = 0; s < 2; ++s) {
        int ar = rb + s * 16 + mrow;
        if (ar >= N_NODES) ar = N_NODES - 1;
        const ushort* ap = hf + (size_t)ar * HID + quad * 8;
#pragma unroll
        for (int kc = 0; kc < 4; ++kc) a[s][kc] = *(const f16x8*)(ap + kc * 32);
    }
    // W fragments: all three mats, distinct registers
    f16x8 bQ[4], bK[4], bV[4];
#pragma unroll
    for (int kc = 0; kc < 4; ++kc) {
        const int off = c * HID + kc * 32 + quad * 8;
        bQ[kc] = *(const f16x8*)(wf + off);
        bK[kc] = *(const f16x8*)(wf + 16384 + off);
        bV[kc] = *(const f16x8*)(wf + 32768 + off);
    }

    f32x4 aq[2], ak[2], av[2];
#pragma unroll
    for (int s = 0; s < 2; ++s) {
        aq[s] = (f32x4){0.f, 0.f, 0.f, 0.f};
        ak[s] = (f32x4){0.f, 0.f, 0.f, 0.f};
        av[s] = (f32x4){0.f, 0.f, 0.f, 0.f};
    }
#pragma unroll
    for (int s = 0; s < 2; ++s)
#pragma unroll
        for (int kc = 0; kc < 4; ++kc) {
            aq[s] = __builtin_amdgcn_mfma_f32_16x16x32_f16(a[s][kc], bQ[kc], aq[s], 0, 0, 0);
            ak[s] = __builtin_amdgcn_mfma_f32_16x16x32_f16(a[s][kc], bK[kc], ak[s], 0, 0, 0);
            av[s] = __builtin_amdgcn_mfma_f32_16x16x32_f16(a[s][kc], bV[kc], av[s], 0, 0, 0);
        }

    const float bqc = bq[c], bkc = bk[c], bvc = bv[c];
    const bool  lo  = (mrow & 8) == 0;
    const int   i   = mrow & 7;                          // = dim-pair t
#pragma unroll
    for (int s = 0; s < 2; ++s)
#pragma unroll
        for (int r = 0; r < 4; ++r) {
            const int orow = rb + s * 16 + quad * 4 + r;
            uint qv = f2h_bits((aq[s][r] + bqc) * 0.25f);  // q pre-scaled 1/sqrt(d)
            uint kb = f2h_bits(ak[s][r] + bkc);
            uint vb = f2h_bits(av[s][r] + bvc);
            uint qh = __shfl_xor((int)qv, 8);
            uint kh = __shfl_xor((int)kb, 8);
            uint vh = __shfl_xor((int)vb, 8);
            if (lo && orow < N_NODES) {
                const size_t base = (size_t)orow * 64 + 8 * T + i;
                qp[base] = qv | (qh << 16);
                kv[base] = make_uint2(kb | (kh << 16), vb | (vh << 16));
            }
        }
}

// ---------------------------------------------------------------------------
// attn + output projection, FUSED (round-3 budget: gemm_out was ~40-55 us and
// row-local — out[i] = ao[i] @ WoT needs only node i's attn row). One
// 512-thread block owns 64 nodes: 8 waves each run the unchanged (memory-
// ceiling-pinned) attn gather for 8 nodes serially, store normalized rows to
// a padded LDS tile, sync, then each wave MFMAs one 16-col tile vs the
// k-permuted Wo. Deletes the gemm_out dispatch + the 25.6 MB ao round-trip.
// attn gather structure unchanged: lane = (half, t); 32 lanes read one full
// 512 B kv row; head = 4-lane quad -> 2-shfl butterfly; 8-edge unroll with
// 4 independent register banks.
__device__ __forceinline__ void pair_acc(uint4 rr, uint2 qu,
                                         float& l, float* O)
{
    float p = __builtin_amdgcn_fdot2(as_h2(rr.x), as_h2(qu.x), 0.f, false);
    p = __builtin_amdgcn_fdot2(as_h2(rr.z), as_h2(qu.y), p, false);
    p += __shfl_xor(p, 1);
    p += __shfl_xor(p, 2);
    const float ex = __expf(p);
    l += ex;
    const f16x2 va = as_h2(rr.y), vb = as_h2(rr.w);
    O[0] += ex * (float)va[0];
    O[1] += ex * (float)va[1];
    O[2] += ex * (float)vb[0];
    O[3] += ex * (float)vb[1];
}

__device__ __forceinline__ void pair_acc_m(uint4 rr, uint2 qu, bool ok,
                                           float& l, float* O)
{
    float p = __builtin_amdgcn_fdot2(as_h2(rr.x), as_h2(qu.x), 0.f, false);
    p = __builtin_amdgcn_fdot2(as_h2(rr.z), as_h2(qu.y), p, false);
    p += __shfl_xor(p, 1);
    p += __shfl_xor(p, 2);
    const float ex = ok ? __expf(p) : 0.f;
    l += ex;
    const f16x2 va = as_h2(rr.y), vb = as_h2(rr.w);
    O[0] += ex * (float)va[0];
    O[1] += ex * (float)va[1];
    O[2] += ex * (float)vb[0];
    O[3] += ex * (float)vb[1];
}

#define ALS_STRIDE 136   // 128 + 8 pad: ds_read_b128 rows land ~2-way (free)

__global__ __launch_bounds__(512) void attn_out(
    const uint* __restrict__ qp, const uint2* __restrict__ kv,
    const int* __restrict__ cnt, const ushort* __restrict__ slots,
    const ushort* __restrict__ wfo, const float* __restrict__ bo,
    float* __restrict__ out)
{
    __shared__ ushort als[64][ALS_STRIDE];   // 17.4 KB

    const int tid  = threadIdx.x;
    const int lane = tid & 63;
    const int w    = tid >> 6;               // wave 0..7
    const int rb   = blockIdx.x * 64;
    const int half = lane >> 5;              // edge-of-pair selector
    const int t    = lane & 31;              // uint4 slot in row

    const uint4* base = (const uint4*)kv;    // row = 32 uint4

    // ---------------- attn phase: 8 nodes per wave ----------------
    for (int it = 0; it < 8; ++it) {
        const int local = w * 8 + it;
        const int node  = rb + local;
        if (node < N_NODES) {
            // q dim-pairs (2t, 2t+1): head t>>2, dims 4(t&3)..+3 (pre-scaled)
            const uint2 qu = *(const uint2*)(qp + (size_t)node * 64 + 2 * t);

            int deg = cnt[node << 4];            // padded counter
            if (deg > CAP) deg = CAP;
            const int myslot = (lane < deg) ? (int)slots[(size_t)node * CAP + lane] : 0;

            float l0 = 0.f, l1 = 0.f, l2 = 0.f, l3 = 0.f;
            float O0[4] = {0,0,0,0}, O1[4] = {0,0,0,0};
            float O2[4] = {0,0,0,0}, O3[4] = {0,0,0,0};

            int j = 0;
            for (; j + 8 <= deg; j += 8) {
                const int s0 = __shfl(myslot, j + half);
                const int s1 = __shfl(myslot, j + 2 + half);
                const int s2 = __shfl(myslot, j + 4 + half);
                const int s3 = __shfl(myslot, j + 6 + half);
                const uint4 r0 = base[(size_t)s0 * 32 + t];
                const uint4 r1 = base[(size_t)s1 * 32 + t];
                const uint4 r2 = base[(size_t)s2 * 32 + t];
                const uint4 r3 = base[(size_t)s3 * 32 + t];
                pair_acc(r0, qu, l0, O0);
                pair_acc(r1, qu, l1, O1);
                pair_acc(r2, qu, l2, O2);
                pair_acc(r3, qu, l3, O3);
            }
            for (; j < deg; j += 2) {
                const int e = j + half;
                const int s = __shfl(myslot, e);   // lanes >= deg hold 0: safe
                const uint4 rr = base[(size_t)s * 32 + t];
                pair_acc_m(rr, qu, e < deg, l0, O0);
            }

            float l = (l0 + l1) + (l2 + l3);
            float Of[4];
            Of[0] = (O0[0] + O1[0]) + (O2[0] + O3[0]);
            Of[1] = (O0[1] + O1[1]) + (O2[1] + O3[1]);
            Of[2] = (O0[2] + O1[2]) + (O2[2] + O3[2]);
            Of[3] = (O0[3] + O1[3]) + (O2[3] + O3[3]);

            // merge the two halves (each processed its own edge subset)
            l += __shfl_xor(l, 32);
            Of[0] += __shfl_xor(Of[0], 32);
            Of[1] += __shfl_xor(Of[1], 32);
            Of[2] += __shfl_xor(Of[2], 32);
            Of[3] += __shfl_xor(Of[3], 32);

            const float inv = (l > 0.f) ? 1.f / l : 0.f;  // deg-0 -> 0

            if (half == 0) {                 // lanes 0..31: 8 B each, contiguous
                ushort4 st;
                st.x = f2h_bits(Of[0] * inv);
                st.y = f2h_bits(Of[1] * inv);
                st.z = f2h_bits(Of[2] * inv);
                st.w = f2h_bits(Of[3] * inv);
                *(ushort4*)&als[local][4 * t] = st;
            }
        } else if (half == 0) {
            *(ushort4*)&als[local][4 * t] = (ushort4){0, 0, 0, 0};
        }
    }

    __syncthreads();

    // ---------------- output-projection phase ----------------
    const int mrow = lane & 15;
    const int quad = lane >> 4;
    const int c    = w * 16 + mrow;          // output col 0..127

    f16x8 bfr[4];
#pragma unroll
    for (int kc = 0; kc < 4; ++kc)
        bfr[kc] = *(const f16x8*)(wfo + c * HID + kc * 32 + quad * 8);

    f32x4 acc[4];
#pragma unroll
    for (int s = 0; s < 4; ++s) acc[s] = (f32x4){0.f, 0.f, 0.f, 0.f};

#pragma unroll
    for (int s = 0; s < 4; ++s) {
        f16x8 afr[4];
#pragma unroll
        for (int kc = 0; kc < 4; ++kc)
            afr[kc] = *(const f16x8*)&als[s * 16 + mrow][quad * 8 + kc * 32];
#pragma unroll
        for (int kc = 0; kc < 4; ++kc)
            acc[s] = __builtin_amdgcn_mfma_f32_16x16x32_f16(afr[kc], bfr[kc], acc[s], 0, 0, 0);
    }

    const float bc = bo[c];
#pragma unroll
    for (int s = 0; s < 4; ++s)
#pragma unroll
        for (int r = 0; r < 4; ++r) {
            const int orow = rb + s * 16 + quad * 4 + r;
            if (orow < N_NODES)
                out[(size_t)orow * HID + c] = acc[s][r] + bc;
        }
}

// ---------------------------------------------------------------------------
extern "C" void kernel_launch(void* const* d_in, const int* in_sizes, int n_in,
                              void* d_out, int out_size, void* d_ws, size_t ws_size,
                              hipStream_t stream)
{
    const float* h    = (const float*)d_in[0];
    const int*   rows = (const int*)  d_in[1];
    const int*   cols = (const int*)  d_in[2];
    const float* Wq   = (const float*)d_in[3];
    const float* bq   = (const float*)d_in[4];
    const float* Wk   = (const float*)d_in[5];
    const float* bk   = (const float*)d_in[6];
    const float* Wv   = (const float*)d_in[7];
    const float* bv   = (const float*)d_in[8];
    const float* Wo   = (const float*)d_in[9];
    const float* bo   = (const float*)d_in[10];
    float* out = (float*)d_out;

    char* ws = (char*)d_ws;
    uint*   qp    = (uint*)ws;    ws += (size_t)N_NODES * 64 * 4;   // 12.8 MB
    uint2*  kv    = (uint2*)ws;   ws += (size_t)N_NODES * 64 * 8;   // 25.6 MB
    ushort* hf    = (ushort*)ws;  ws += (size_t)N_NODES * HID * 2;  // 12.8 MB
    ushort* wf    = (ushort*)ws;  ws += 4 * 16384 * 2;              // 128 KB
    int*    cnt   = (int*)ws;     ws += (size_t)N_NODES * 64;       // 3.2 MB padded
    ushort* slots = (ushort*)ws;  // N*CAP ushorts, 6.4 MB

    hipMemsetAsync(cnt, 0, (size_t)N_NODES * 64, stream);

    prep<<<PREP_BLK, dim3(256), 0, stream>>>(h, Wq, Wk, Wv, Wo, hf, wf,
                                             rows, cols, cnt, slots);
    gemm_qkv<<<QKV_BX, dim3(512), 0, stream>>>(hf, wf, bq, bk, bv, qp, kv);
    attn_out<<<AO_BLK, dim3(512), 0, stream>>>(qp, kv, cnt, slots,
                                               wf + 3 * 16384, bo, out);
}

// Round 5
// 240.295 us; speedup vs baseline: 1.0523x; 1.0448x over previous
//
#include <hip/hip_runtime.h>
#include <math.h>

#define N_NODES 50000
#define N_EDGES 800000
#define HID 128
#define CAP 64                              // max in-degree; Poisson(16) -> P(>64) ~ 1e-18

// prep grid partition: [scatter | weight-cvt | h-cvt]  (R2-verified structure:
// scatter latency hides under streaming cvt; NEVER co-schedule scatter w/ MFMA)
#define SCAT_TH   (N_EDGES / 8)             // 100000 threads, 8 edges each
#define SCAT_BLK  ((SCAT_TH + 255) / 256)   // 391
#define WCVT_BLK  64                        // 4 mats x 4096 float4 / 256
#define HCVT_BLK  (N_NODES * HID / 4 / 256) // 6250
#define PREP_BLK  (SCAT_BLK + WCVT_BLK + HCVT_BLK)

#define QKV_BX    ((N_NODES + 31) / 32)     // 1563 blocks, 512 threads (8 head-waves)
#define ATTN_BLK  ((N_NODES + 3) / 4)       // 12500 blocks (1 wave = 1 node: max TLP)
#define OUT_BLK   ((N_NODES + 63) / 64)     // 782

typedef _Float16 f16_t;
typedef f16_t f16x8 __attribute__((ext_vector_type(8)));
typedef f16_t f16x2 __attribute__((ext_vector_type(2)));
typedef float f32x4 __attribute__((ext_vector_type(4)));

__device__ __forceinline__ ushort f2h_bits(float x) {
    union { f16_t h; ushort u; } c; c.h = (f16_t)x; return c.u;
}
__device__ __forceinline__ f16x2 as_h2(uint u) {
    union { uint u_; f16x2 h; } c; c.u_ = u; return c.h;
}

// ---------------------------------------------------------------------------
// prep: one grid, three independent jobs co-scheduled (exact R2 structure).
//   blocks [0, SCAT_BLK)    : edge scatter — 8 edges/thread, int4 loads,
//                             8 returning atomics in flight, 64B-padded cnt
//   next WCVT_BLK           : Wq/Wk/Wv f32 -> f16 (hidden-k order);
//                             Wo f32 -> f16 with k-axis PERMUTED head-major
//                             p = (k&7)*16 + (k>>3)  (matches attn ao layout)
//   next HCVT_BLK           : h f32 -> f16 (BW-bound; hides scatter latency)
__global__ __launch_bounds__(256) void prep(
    const float* __restrict__ h,
    const float* __restrict__ Wq, const float* __restrict__ Wk,
    const float* __restrict__ Wv, const float* __restrict__ Wo,
    ushort* __restrict__ hf, ushort* __restrict__ wf,     // wf: 4 mats concat
    const int* __restrict__ rows, const int* __restrict__ cols,
    int* __restrict__ cnt, ushort* __restrict__ slots)
{
    const int b = blockIdx.x;
    const int tid = threadIdx.x;

    if (b < SCAT_BLK) {
        const int t = b * 256 + tid;
        if (t < SCAT_TH) {
            const int4* r4 = (const int4*)rows + (size_t)t * 2;
            const int4* c4 = (const int4*)cols + (size_t)t * 2;
            int4 ra = r4[0], rb2 = r4[1];
            int4 ca = c4[0], cb = c4[1];
            const int r[8] = {ra.x, ra.y, ra.z, ra.w, rb2.x, rb2.y, rb2.z, rb2.w};
            const int c[8] = {ca.x, ca.y, ca.z, ca.w, cb.x, cb.y, cb.z, cb.w};
            int p[8];
#pragma unroll
            for (int u = 0; u < 8; ++u)
                p[u] = atomicAdd(&cnt[r[u] << 4], 1);     // 64B-padded counter
#pragma unroll
            for (int u = 0; u < 8; ++u)
                if (p[u] < CAP) slots[(size_t)r[u] * CAP + p[u]] = (ushort)c[u];
        }
    } else if (b < SCAT_BLK + WCVT_BLK) {
        const int t = (b - SCAT_BLK) * 256 + tid;         // [0, 16384)
        const int m = t >> 12, i = t & 4095;
        const float* src = (m == 0) ? Wq : (m == 1) ? Wk : (m == 2) ? Wv : Wo;
        float4 f = ((const float4*)src)[i];
        if (m < 3) {
            ushort4 o;
            o.x = f2h_bits(f.x); o.y = f2h_bits(f.y);
            o.z = f2h_bits(f.z); o.w = f2h_bits(f.w);
            ((ushort4*)(wf + m * 16384))[i] = o;
        } else {
            // Wo: permute k-axis to head-major p = head*16 + dim
            const int c  = i >> 5;            // output col (Wo row)
            const int k0 = (i & 31) * 4;      // hidden k of f.x
            const int d  = k0 >> 3;           // dim group (k0 % 8 in {0,4})
            ushort* wo = wf + 3 * 16384 + c * HID + d;
            wo[((k0 + 0) & 7) << 4] = f2h_bits(f.x);
            wo[((k0 + 1) & 7) << 4] = f2h_bits(f.y);
            wo[((k0 + 2) & 7) << 4] = f2h_bits(f.z);
            wo[((k0 + 3) & 7) << 4] = f2h_bits(f.w);
        }
    } else {
        const int t = (b - SCAT_BLK - WCVT_BLK) * 256 + tid;  // [0, 1.6M)
        float4 f = ((const float4*)h)[t];
        ushort4 o;
        o.x = f2h_bits(f.x); o.y = f2h_bits(f.y);
        o.z = f2h_bits(f.z); o.w = f2h_bits(f.w);
        ((ushort4*)hf)[t] = o;
    }
}

// ---------------------------------------------------------------------------
// QKV projection, MFMA 16x16x32 f16, 8 head-waves per 32-row strip.
// Round-4 post-mortem: R3 counters showed WRITE_SIZE 2x ideal — the old
// epilogue's half-wave 32B qp / 64B kv masked stores caused partial-line L2
// writebacks. New epilogue: lo-lanes stage packed results in padded LDS
// (qls stride 66 dwords, kls stride 65 uint2 -> <=2-way bank alias, free),
// sync, then the whole block stores the tile with fully-coalesced dwordx4
// (qp: 512 x 16B, kv: 512 x 32B) — every L2 line written complete.
// Layout (verified rounds 1-4): wave T = head, cols c = 16*(mrow&7) +
// (mrow>=8)*8 + T; pack p = 8T + (mrow&7):
//   qp[row*64 + 8h + t]  = [q_{2t} | q_{2t+1}] of head h (*0.25)
//   kv[row*64 + 8h + t]  = { [k_2t|k_2t+1], [v_2t|v_2t+1] } of head h
#define QLS_STRIDE 66   // dwords per row (64 + 2 pad)
#define KLS_STRIDE 65   // uint2 per row (64 + 1 pad)

__global__ __launch_bounds__(512) void gemm_qkv(
    const ushort* __restrict__ hf, const ushort* __restrict__ wf,
    const float* __restrict__ bq, const float* __restrict__ bk,
    const float* __restrict__ bv,
    uint* __restrict__ qp, uint2* __restrict__ kv)
{
    __shared__ uint  qls[32 * QLS_STRIDE];   // 8448 B
    __shared__ uint2 kls[32 * KLS_STRIDE];   // 16640 B

    const int tid  = threadIdx.x;
    const int lane = tid & 63;
    const int T    = tid >> 6;                           // head 0..7
    const int mrow = lane & 15;
    const int quad = lane >> 4;
    const int rb   = blockIdx.x * 32;
    const int c    = ((mrow & 7) << 4) + ((mrow >> 3) << 3) + T;  // hidden col

    // A fragments (2 strips x 4 k-chunks), row-clamped at N
    f16x8 a[2][4];
#pragma unroll
    for (int s = 0; s < 2; ++s) {
        int ar = rb + s * 16 + mrow;
        if (ar >= N_NODES) ar = N_NODES - 1;
        const ushort* ap = hf + (size_t)ar * HID + quad * 8;
#pragma unroll
        for (int kc = 0; kc < 4; ++kc) a[s][kc] = *(const f16x8*)(ap + kc * 32);
    }
    // W fragments: all three mats, distinct registers
    f16x8 bQ[4], bK[4], bV[4];
#pragma unroll
    for (int kc = 0; kc < 4; ++kc) {
        const int off = c * HID + kc * 32 + quad * 8;
        bQ[kc] = *(const f16x8*)(wf + off);
        bK[kc] = *(const f16x8*)(wf + 16384 + off);
        bV[kc] = *(const f16x8*)(wf + 32768 + off);
    }

    f32x4 aq[2], ak[2], av[2];
#pragma unroll
    for (int s = 0; s < 2; ++s) {
        aq[s] = (f32x4){0.f, 0.f, 0.f, 0.f};
        ak[s] = (f32x4){0.f, 0.f, 0.f, 0.f};
        av[s] = (f32x4){0.f, 0.f, 0.f, 0.f};
    }
#pragma unroll
    for (int s = 0; s < 2; ++s)
#pragma unroll
        for (int kc = 0; kc < 4; ++kc) {
            aq[s] = __builtin_amdgcn_mfma_f32_16x16x32_f16(a[s][kc], bQ[kc], aq[s], 0, 0, 0);
            ak[s] = __builtin_amdgcn_mfma_f32_16x16x32_f16(a[s][kc], bK[kc], ak[s], 0, 0, 0);
            av[s] = __builtin_amdgcn_mfma_f32_16x16x32_f16(a[s][kc], bV[kc], av[s], 0, 0, 0);
        }

    const float bqc = bq[c], bkc = bk[c], bvc = bv[c];
    const bool  lo  = (mrow & 8) == 0;
    const int   i   = mrow & 7;                          // = dim-pair t
#pragma unroll
    for (int s = 0; s < 2; ++s)
#pragma unroll
        for (int r = 0; r < 4; ++r) {
            const int lrow = s * 16 + quad * 4 + r;      // local row 0..31
            uint qv = f2h_bits((aq[s][r] + bqc) * 0.25f);  // q pre-scaled 1/sqrt(d)
            uint kb = f2h_bits(ak[s][r] + bkc);
            uint vb = f2h_bits(av[s][r] + bvc);
            uint qh = __shfl_xor((int)qv, 8);
            uint kh = __shfl_xor((int)kb, 8);
            uint vh = __shfl_xor((int)vb, 8);
            if (lo) {
                qls[lrow * QLS_STRIDE + 8 * T + i] = qv | (qh << 16);
                kls[lrow * KLS_STRIDE + 8 * T + i] = make_uint2(kb | (kh << 16), vb | (vh << 16));
            }
        }

    __syncthreads();

    // cooperative coalesced stores: qp tile = 512 x uint4, kv tile = 1024 x uint4
    {
        const int row = tid >> 4;                        // 0..31
        if (rb + row < N_NODES) {
            const int col4 = (tid & 15) * 4;
            uint4 v = *(const uint4*)&qls[row * QLS_STRIDE + col4];
            ((uint4*)(qp + (size_t)rb * 64))[tid] = v;
        }
    }
#pragma unroll
    for (int k = 0; k < 2; ++k) {
        const int u   = tid + k * 512;                   // uint4 index [0,1024)
        const int row = u >> 5;                          // 32 uint4 per row
        if (rb + row < N_NODES) {
            const int q4 = u & 31;
            uint4 v = *(const uint4*)&kls[row * KLS_STRIDE + q4 * 2];
            ((uint4*)(kv + (size_t)rb * 64))[u] = v;
        }
    }
}

// ---------------------------------------------------------------------------
// attn, hybrid structure (R2-verified; pinned at the random-512B-gather memory
// ceiling: multiple structures all measured 56 us / 182 MB / 3.55 TB/s; the
// ceiling is concurrency-fed — one wave per node, 50000 waves, max TLP).
// Lane = (half, t): half = lane>>5 picks which edge of a pair, t = lane&31
// owns the row's uint4 slot t. 32 lanes read one FULL 512 B kv row
// contiguously; wave covers 2 edges per load. Head = 4-lane quad -> butterfly
// is 2 shfls (xor 1,2). 8-edge unroll, 4 independent register banks.
__device__ __forceinline__ void pair_acc(uint4 rr, uint2 qu,
                                         float& l, float* O)
{
    float p = __builtin_amdgcn_fdot2(as_h2(rr.x), as_h2(qu.x), 0.f, false);
    p = __builtin_amdgcn_fdot2(as_h2(rr.z), as_h2(qu.y), p, false);
    p += __shfl_xor(p, 1);
    p += __shfl_xor(p, 2);
    const float ex = __expf(p);
    l += ex;
    const f16x2 va = as_h2(rr.y), vb = as_h2(rr.w);
    O[0] += ex * (float)va[0];
    O[1] += ex * (float)va[1];
    O[2] += ex * (float)vb[0];
    O[3] += ex * (float)vb[1];
}

__device__ __forceinline__ void pair_acc_m(uint4 rr, uint2 qu, bool ok,
                                           float& l, float* O)
{
    float p = __builtin_amdgcn_fdot2(as_h2(rr.x), as_h2(qu.x), 0.f, false);
    p = __builtin_amdgcn_fdot2(as_h2(rr.z), as_h2(qu.y), p, false);
    p += __shfl_xor(p, 1);
    p += __shfl_xor(p, 2);
    const float ex = ok ? __expf(p) : 0.f;
    l += ex;
    const f16x2 va = as_h2(rr.y), vb = as_h2(rr.w);
    O[0] += ex * (float)va[0];
    O[1] += ex * (float)va[1];
    O[2] += ex * (float)vb[0];
    O[3] += ex * (float)vb[1];
}

__global__ __launch_bounds__(256) void attn(
    const uint* __restrict__ qp, const uint2* __restrict__ kv,
    const int* __restrict__ cnt, const ushort* __restrict__ slots,
    ushort* __restrict__ ao)
{
    const int lane = threadIdx.x & 63;
    const int node = blockIdx.x * 4 + (threadIdx.x >> 6);
    if (node >= N_NODES) return;
    const int half = lane >> 5;              // edge-of-pair selector
    const int t    = lane & 31;              // uint4 slot in row

    // q dim-pairs (2t, 2t+1): head t>>2, dims 4(t&3)..+3 (pre-scaled)
    const uint2 qu = *(const uint2*)(qp + (size_t)node * 64 + 2 * t);

    int deg = cnt[node << 4];                // padded counter
    if (deg > CAP) deg = CAP;
    const int myslot = (lane < deg) ? (int)slots[(size_t)node * CAP + lane] : 0;

    float l0 = 0.f, l1 = 0.f, l2 = 0.f, l3 = 0.f;
    float O0[4] = {0,0,0,0}, O1[4] = {0,0,0,0};
    float O2[4] = {0,0,0,0}, O3[4] = {0,0,0,0};

    const uint4* base = (const uint4*)kv;    // row = 32 uint4

    int j = 0;
    for (; j + 8 <= deg; j += 8) {
        const int s0 = __shfl(myslot, j + half);
        const int s1 = __shfl(myslot, j + 2 + half);
        const int s2 = __shfl(myslot, j + 4 + half);
        const int s3 = __shfl(myslot, j + 6 + half);
        const uint4 r0 = base[(size_t)s0 * 32 + t];
        const uint4 r1 = base[(size_t)s1 * 32 + t];
        const uint4 r2 = base[(size_t)s2 * 32 + t];
        const uint4 r3 = base[(size_t)s3 * 32 + t];
        pair_acc(r0, qu, l0, O0);
        pair_acc(r1, qu, l1, O1);
        pair_acc(r2, qu, l2, O2);
        pair_acc(r3, qu, l3, O3);
    }
    for (; j < deg; j += 2) {
        const int e = j + half;
        const int s = __shfl(myslot, e);     // lanes >= deg hold 0: safe
        const uint4 rr = base[(size_t)s * 32 + t];
        pair_acc_m(rr, qu, e < deg, l0, O0);
    }

    float l = (l0 + l1) + (l2 + l3);
    float Of[4];
    Of[0] = (O0[0] + O1[0]) + (O2[0] + O3[0]);
    Of[1] = (O0[1] + O1[1]) + (O2[1] + O3[1]);
    Of[2] = (O0[2] + O1[2]) + (O2[2] + O3[2]);
    Of[3] = (O0[3] + O1[3]) + (O2[3] + O3[3]);

    // merge the two halves (each processed its own edge subset)
    l += __shfl_xor(l, 32);
    Of[0] += __shfl_xor(Of[0], 32);
    Of[1] += __shfl_xor(Of[1], 32);
    Of[2] += __shfl_xor(Of[2], 32);
    Of[3] += __shfl_xor(Of[3], 32);

    const float inv = (l > 0.f) ? 1.f / l : 0.f;   // deg-0 -> 0 (bo added later)

    if (half == 0) {                        // lanes 0..31 store 8 B each, contiguous
        ushort4 st;
        st.x = f2h_bits(Of[0] * inv);
        st.y = f2h_bits(Of[1] * inv);
        st.z = f2h_bits(Of[2] * inv);
        st.w = f2h_bits(Of[3] * inv);
        *(ushort4*)(ao + (size_t)node * HID + 4 * t) = st;
    }
}

// ---------------------------------------------------------------------------
// Output projection, flat pipeline: all 24 loads (16 A + 8 W f16) up front,
// then 32 MFMAs. 64-row blocks, wave owns 2 n-tiles (32 cols).
// A (ao) is head-major in k; wfo is the k-permuted Wo — the MFMA contraction
// index just runs over the permuted order on both sides.
__global__ __launch_bounds__(256) void gemm_out(
    const ushort* __restrict__ A, const ushort* __restrict__ wfo,
    const float* __restrict__ bias, float* __restrict__ out)
{
    const int lane = threadIdx.x & 63;
    const int wid  = threadIdx.x >> 6;
    const int mrow = lane & 15;
    const int quad = lane >> 4;
    const int rb   = blockIdx.x * 64;

    const int c0 = wid * 32 + mrow;
    const int c1 = c0 + 16;

    f16x8 a[4][4];
#pragma unroll
    for (int s = 0; s < 4; ++s) {
        int ar = rb + s * 16 + mrow;
        if (ar >= N_NODES) ar = N_NODES - 1;
        const ushort* ap = A + (size_t)ar * HID + quad * 8;
#pragma unroll
        for (int kc = 0; kc < 4; ++kc) a[s][kc] = *(const f16x8*)(ap + kc * 32);
    }
    f16x8 b0[4], b1[4];
#pragma unroll
    for (int kc = 0; kc < 4; ++kc) {
        b0[kc] = *(const f16x8*)(wfo + c0 * HID + kc * 32 + quad * 8);
        b1[kc] = *(const f16x8*)(wfo + c1 * HID + kc * 32 + quad * 8);
    }

    f32x4 acc[4][2];
#pragma unroll
    for (int s = 0; s < 4; ++s) {
        acc[s][0] = (f32x4){0.f, 0.f, 0.f, 0.f};
        acc[s][1] = (f32x4){0.f, 0.f, 0.f, 0.f};
    }
#pragma unroll
    for (int s = 0; s < 4; ++s)
#pragma unroll
        for (int kc = 0; kc < 4; ++kc) {
            acc[s][0] = __builtin_amdgcn_mfma_f32_16x16x32_f16(a[s][kc], b0[kc], acc[s][0], 0, 0, 0);
            acc[s][1] = __builtin_amdgcn_mfma_f32_16x16x32_f16(a[s][kc], b1[kc], acc[s][1], 0, 0, 0);
        }

    const float bc0 = bias[c0], bc1 = bias[c1];
#pragma unroll
    for (int s = 0; s < 4; ++s)
#pragma unroll
        for (int r = 0; r < 4; ++r) {
            const int orow = rb + s * 16 + quad * 4 + r;
            if (orow < N_NODES) {
                out[(size_t)orow * HID + c0] = acc[s][0][r] + bc0;
                out[(size_t)orow * HID + c1] = acc[s][1][r] + bc1;
            }
        }
}

// ---------------------------------------------------------------------------
extern "C" void kernel_launch(void* const* d_in, const int* in_sizes, int n_in,
                              void* d_out, int out_size, void* d_ws, size_t ws_size,
                              hipStream_t stream)
{
    const float* h    = (const float*)d_in[0];
    const int*   rows = (const int*)  d_in[1];
    const int*   cols = (const int*)  d_in[2];
    const float* Wq   = (const float*)d_in[3];
    const float* bq   = (const float*)d_in[4];
    const float* Wk   = (const float*)d_in[5];
    const float* bk   = (const float*)d_in[6];
    const float* Wv   = (const float*)d_in[7];
    const float* bv   = (const float*)d_in[8];
    const float* Wo   = (const float*)d_in[9];
    const float* bo   = (const float*)d_in[10];
    float* out = (float*)d_out;

    char* ws = (char*)d_ws;
    uint*   qp    = (uint*)ws;    ws += (size_t)N_NODES * 64 * 4;   // 12.8 MB
    uint2*  kv    = (uint2*)ws;   ws += (size_t)N_NODES * 64 * 8;   // 25.6 MB
    ushort* hf    = (ushort*)ws;  ws += (size_t)N_NODES * HID * 2;  // 12.8 MB
    ushort* ao    = (ushort*)ws;  ws += (size_t)N_NODES * HID * 2;  // 12.8 MB
    ushort* wf    = (ushort*)ws;  ws += 4 * 16384 * 2;              // 128 KB
    int*    cnt   = (int*)ws;     ws += (size_t)N_NODES * 64;       // 3.2 MB padded
    ushort* slots = (ushort*)ws;  // N*CAP ushorts, 6.4 MB

    hipMemsetAsync(cnt, 0, (size_t)N_NODES * 64, stream);

    prep<<<PREP_BLK, dim3(256), 0, stream>>>(h, Wq, Wk, Wv, Wo, hf, wf,
                                             rows, cols, cnt, slots);
    gemm_qkv<<<QKV_BX, dim3(512), 0, stream>>>(hf, wf, bq, bk, bv, qp, kv);
    attn<<<ATTN_BLK, dim3(256), 0, stream>>>(qp, kv, cnt, slots, ao);
    gemm_out<<<OUT_BLK, dim3(256), 0, stream>>>(ao, wf + 3 * 16384, bo, out);
}